// Round 6
// baseline (15420.419 us; speedup 1.0000x reference)
//
#include <hip/hip_runtime.h>
#include <math.h>

// ---------------------------------------------------------------------------
// CurvePredictor R6: swizzled coalesced weight streaming + REAL register ring.
// 128 blocks x 512 threads (8 waves, launch_bounds(512,1) -> big VGPR budget;
// R5's 1024-thread blocks forced a 64-VGPR budget that collapsed the prefetch
// pipeline into serialized just-in-time loads -> ~35 GB/s/CU latency wall).
// Each block owns 16 batch rows; wave w owns 32 hidden cols (2 col-tiles).
// Weights pre-swizzled so every MFMA B-fragment is one fully-coalesced 1 KB
// wave load. Distance-2 register ring (3 slots x 4 gates) per gemm keeps
// ~8+ loads in flight per wave with compiler-exact vmcnt scheduling.
// Double-buffered h0/h1 in LDS, 3 barriers/step, zero cross-block sync.
// ---------------------------------------------------------------------------

typedef short s8v __attribute__((ext_vector_type(8)));   // 8 x bf16
typedef float f4v __attribute__((ext_vector_type(4)));   // 4 x f32

#define HSTR 264            // LDS h-row stride in shorts (33*16B)
#define DSTR 136

__device__ __forceinline__ f4v mfma16(s8v a, s8v b, f4v c){
  return __builtin_amdgcn_mfma_f32_16x16x32_bf16(a, b, c, 0, 0, 0);
}
__device__ __forceinline__ short f2bf(float f){
  unsigned u = __float_as_uint(f);
  u = u + 0x7FFFu + ((u >> 16) & 1u);
  return (short)(u >> 16);
}
__device__ __forceinline__ float wred(float v){
  #pragma unroll
  for (int o = 32; o; o >>= 1) v += __shfl_xor(v, o);
  return v;
}
__device__ __forceinline__ float sigm(float x){ return 1.0f / (1.0f + __expf(-x)); }
__device__ __forceinline__ float tnh(float x){
  x = fminf(15.0f, fmaxf(-15.0f, x));
  float e = __expf(2.0f * x);
  return (e - 1.0f) / (e + 1.0f);
}
__device__ __forceinline__ float gelu(float v){
  return 0.5f * v * (1.0f + erff(v * 0.70710678118654752440f));
}

// ws layout (shorts), swizzled for coalesced B-frag loads (same as R5):
// main matrices (1024x256): elem = s*16384 + g*4096 + kk*512 + lane*8 + j
//   lane = q*16+m16, hid = s*16+m16, k = kk*32+q*8+j, gate-row = g*256+hid
//   [0,262144) Wih0  [262144,524288) Whh0  [524288,786432) Wih1  [786432,1048576) Whh1
// W3 [128][256]: 1048576 + s2*4096 + kk*512 + lane*8  (row = s2*16+m16)
// W4 padded [16][128]: 1081344 + kk*512 + lane*8      (row = m16, kk<4)
__global__ void prep_kernel(
    const float* __restrict__ Wih0, const float* __restrict__ Whh0,
    const float* __restrict__ Wih1, const float* __restrict__ Whh1,
    const float* __restrict__ W3,   const float* __restrict__ W4,
    short* __restrict__ wsb)
{
  const int i = blockIdx.x * 256 + threadIdx.x;
  if (i >= 1083392) return;
  float v;
  if (i < 1048576){
    const int seg = i >> 18;
    const int r   = i & 262143;
    const int s   = r >> 14;
    const int g   = (r >> 12) & 3;
    const int kk  = (r >> 9) & 7;
    const int q   = (r >> 7) & 3;
    const int m16 = (r >> 3) & 15;
    const int j   = r & 7;
    const int hid = s * 16 + m16;
    const int k   = kk * 32 + q * 8 + j;
    const float* mt = (seg == 0) ? Wih0 : (seg == 1) ? Whh0 : (seg == 2) ? Wih1 : Whh1;
    v = mt[(g * 256 + hid) * 256 + k];
  } else if (i < 1081344){
    const int r   = i - 1048576;
    const int s2  = r >> 12;
    const int kk  = (r >> 9) & 7;
    const int q   = (r >> 7) & 3;
    const int m16 = (r >> 3) & 15;
    const int j   = r & 7;
    v = W3[(s2 * 16 + m16) * 256 + kk * 32 + q * 8 + j];
  } else {
    const int r   = i - 1081344;
    const int kk  = (r >> 9) & 3;
    const int q   = (r >> 7) & 3;
    const int m16 = (r >> 3) & 15;
    const int j   = r & 7;
    const int k   = kk * 32 + q * 8 + j;
    v = (m16 < 2) ? W4[m16 * 128 + k] : 0.0f;
  }
  wsb[i] = f2bf(v);
}

// One matrix, this wave's 2 col-tiles, K=256. Distance-2 ring, 3 slots x 4
// gates (48 VGPR). s = kk*2+ct; slot (s+2)%3 loads while slot s%3 feeds MFMA.
__device__ __forceinline__ void gemm_w(
    const short* __restrict__ h, const short* __restrict__ p0,
    const short* __restrict__ p1, int m16, int q, f4v (&acc)[2][4])
{
  s8v ring[3][4];
  #pragma unroll
  for (int g = 0; g < 4; g++) ring[0][g] = *(const s8v*)(p0 + g * 4096);
  #pragma unroll
  for (int g = 0; g < 4; g++) ring[1][g] = *(const s8v*)(p1 + g * 4096);
  s8v a;
  #pragma unroll
  for (int s = 0; s < 16; s++){
    const int kk = s >> 1, ct = s & 1;
    if (s < 14){
      const int s2 = s + 2, k2 = s2 >> 1;
      const short* pp = (s2 & 1) ? p1 : p0;
      #pragma unroll
      for (int g = 0; g < 4; g++)
        ring[s2 % 3][g] = *(const s8v*)(pp + g * 4096 + k2 * 512);
    }
    if (ct == 0) a = *(const s8v*)&h[m16 * HSTR + kk * 32 + q * 8];
    #pragma unroll
    for (int g = 0; g < 4; g++)
      acc[ct][g] = mfma16(a, ring[s % 3][g], acc[ct][g]);
  }
}

__global__ __launch_bounds__(512, 1) void curve_main(
    const float* __restrict__ x,
    const float* __restrict__ W1, const float* __restrict__ b1,
    const float* __restrict__ g1, const float* __restrict__ be1,
    const float* __restrict__ W2, const float* __restrict__ b2,
    const float* __restrict__ g2, const float* __restrict__ be2,
    const float* __restrict__ bih0, const float* __restrict__ bhh0,
    const float* __restrict__ bih1, const float* __restrict__ bhh1,
    const float* __restrict__ b3, const float* __restrict__ b4,
    const short* __restrict__ wsb,
    float* __restrict__ out)
{
  const int tid  = threadIdx.x;
  const int w    = tid >> 6;        // wave 0..7 <-> 32-col hidden slice
  const int lane = tid & 63;
  const int q    = lane >> 4;
  const int m16  = lane & 15;
  const int row0 = blockIdx.x * 16;

  __shared__ __align__(16) short h0b[2][16 * HSTR];
  __shared__ __align__(16) short h1b[2][16 * HSTR];
  __shared__ __align__(16) short dstg[16 * DSTR];

  // --------- encoder: wave w computes batch rows row0 + u*8 + w ------------
  #pragma unroll 1
  for (int u = 0; u < 2; u++){
    const int rr = u * 8 + w;
    const int r  = row0 + rr;
    float xv[5];
    #pragma unroll
    for (int k = 0; k < 5; k++) xv[k] = x[r * 5 + k];
    float a0 = b1[lane], a1 = b1[lane + 64];
    #pragma unroll
    for (int k = 0; k < 5; k++){
      a0 += xv[k] * W1[lane * 5 + k];
      a1 += xv[k] * W1[(lane + 64) * 5 + k];
    }
    a0 = gelu(a0); a1 = gelu(a1);
    float mean = wred(a0 + a1) * (1.0f / 128.0f);
    float d0 = a0 - mean, d1 = a1 - mean;
    float inv = rsqrtf(wred(d0 * d0 + d1 * d1) * (1.0f / 128.0f) + 1e-5f);
    float y0 = d0 * inv * g1[lane]      + be1[lane];
    float y1 = d1 * inv * g1[lane + 64] + be1[lane + 64];

    float acc2[4];
    #pragma unroll
    for (int uu = 0; uu < 4; uu++) acc2[uu] = b2[lane + 64 * uu];
    for (int k = 0; k < 64; k++){
      float v0 = __shfl(y0, k);
      float v1 = __shfl(y1, k);
      #pragma unroll
      for (int uu = 0; uu < 4; uu++){
        const float* wr = W2 + (lane + 64 * uu) * 128;
        acc2[uu] += v0 * wr[k] + v1 * wr[k + 64];
      }
    }
    #pragma unroll
    for (int uu = 0; uu < 4; uu++) acc2[uu] = gelu(acc2[uu]);
    float s = acc2[0] + acc2[1] + acc2[2] + acc2[3];
    mean = wred(s) * (1.0f / 256.0f);
    float vv = 0.0f;
    #pragma unroll
    for (int uu = 0; uu < 4; uu++){ float d = acc2[uu] - mean; vv += d * d; }
    inv = rsqrtf(wred(vv) * (1.0f / 256.0f) + 1e-5f);
    #pragma unroll
    for (int uu = 0; uu < 4; uu++){
      int c = lane + 64 * uu;
      float e = (acc2[uu] - mean) * inv * g2[c] + be2[c];
      h0b[0][rr * HSTR + c] = f2bf(e);       // enc staged in h0 slot 0
    }
  }
  __syncthreads();

  // per-lane swizzled weight bases; slice s = 2w+ct
  const short* pwi0_0 = wsb            + (2 * w    ) * 16384 + (lane << 3);
  const short* pwi0_1 = wsb            + (2 * w + 1) * 16384 + (lane << 3);
  const short* pwh0_0 = wsb +  262144  + (2 * w    ) * 16384 + (lane << 3);
  const short* pwh0_1 = wsb +  262144  + (2 * w + 1) * 16384 + (lane << 3);
  const short* pwi1_0 = wsb +  524288  + (2 * w    ) * 16384 + (lane << 3);
  const short* pwi1_1 = wsb +  524288  + (2 * w + 1) * 16384 + (lane << 3);
  const short* pwh1_0 = wsb +  786432  + (2 * w    ) * 16384 + (lane << 3);
  const short* pwh1_1 = wsb +  786432  + (2 * w + 1) * 16384 + (lane << 3);
  const short* pw3    = wsb + 1048576  + w * 4096 + (lane << 3);
  const short* pw4    = wsb + 1081344  + (lane << 3);

  // ---- xp0 = enc @ Wih0_slice^T + (bih0+bhh0), kept in registers ----
  f4v xp[2][4];
  #pragma unroll
  for (int ct = 0; ct < 2; ct++)
    #pragma unroll
    for (int g = 0; g < 4; g++){
      const int n = g * 256 + w * 32 + ct * 16 + m16;
      const float bi = bih0[n] + bhh0[n];
      f4v t = {bi, bi, bi, bi};
      xp[ct][g] = t;
    }
  gemm_w(&h0b[0][0], pwi0_0, pwi0_1, m16, q, xp);
  __syncthreads();
  for (int i = tid; i < 16 * HSTR; i += 512){ h0b[0][i] = 0; h1b[0][i] = 0; }

  float bs1[2][4];
  #pragma unroll
  for (int ct = 0; ct < 2; ct++)
    #pragma unroll
    for (int g = 0; g < 4; g++){
      const int n = g * 256 + w * 32 + ct * 16 + m16;
      bs1[ct][g] = bih1[n] + bhh1[n];
    }
  const float b3c = b3[w * 16 + m16];
  const float b4v = (m16 < 2) ? b4[m16] : 0.0f;
  float c0[2][4], c1[2][4];
  #pragma unroll
  for (int ct = 0; ct < 2; ct++)
    #pragma unroll
    for (int r = 0; r < 4; r++){ c0[ct][r] = 0.f; c1[ct][r] = 0.f; }
  __syncthreads();

  // --------------------------- recurrence over T ---------------------------
  #pragma unroll 1
  for (int t = 0; t < 256; t++){
    const short* h0in  = h0b[t & 1];
    short*       h0out = h0b[(t + 1) & 1];
    const short* h1in  = h1b[t & 1];
    short*       h1out = h1b[(t + 1) & 1];

    // ---- A: gates0 = xp0 + h0_old @ Whh0^T -> c0, h0_new ----
    {
      f4v acc[2][4];
      #pragma unroll
      for (int ct = 0; ct < 2; ct++)
        #pragma unroll
        for (int g = 0; g < 4; g++) acc[ct][g] = xp[ct][g];
      gemm_w(h0in, pwh0_0, pwh0_1, m16, q, acc);
      #pragma unroll
      for (int ct = 0; ct < 2; ct++)
        #pragma unroll
        for (int r = 0; r < 4; r++){
          float ii = sigm(acc[ct][0][r]);
          float ff = sigm(acc[ct][1][r]);
          float gg = tnh (acc[ct][2][r]);
          float oo = sigm(acc[ct][3][r]);
          c0[ct][r] = ff * c0[ct][r] + ii * gg;
          h0out[(q * 4 + r) * HSTR + w * 32 + ct * 16 + m16] = f2bf(oo * tnh(c0[ct][r]));
        }
    }
    __syncthreads();                             // (1) h0_new visible

    // ---- B: gates1 = bias1 + h0_new@Wih1^T + h1_old@Whh1^T -> c1, h1_new --
    {
      f4v acc[2][4];
      #pragma unroll
      for (int ct = 0; ct < 2; ct++)
        #pragma unroll
        for (int g = 0; g < 4; g++){
          f4v tv = {bs1[ct][g], bs1[ct][g], bs1[ct][g], bs1[ct][g]};
          acc[ct][g] = tv;
        }
      gemm_w(h0out, pwi1_0, pwi1_1, m16, q, acc);
      gemm_w(h1in,  pwh1_0, pwh1_1, m16, q, acc);
      #pragma unroll
      for (int ct = 0; ct < 2; ct++)
        #pragma unroll
        for (int r = 0; r < 4; r++){
          float ii = sigm(acc[ct][0][r]);
          float ff = sigm(acc[ct][1][r]);
          float gg = tnh (acc[ct][2][r]);
          float oo = sigm(acc[ct][3][r]);
          c1[ct][r] = ff * c1[ct][r] + ii * gg;
          h1out[(q * 4 + r) * HSTR + w * 32 + ct * 16 + m16] = f2bf(oo * tnh(c1[ct][r]));
        }
    }
    __syncthreads();                             // (2) h1_new visible

    // ---- C: d = gelu(h1_new @ W3^T + b3), wave w -> d cols w*16+m16 ----
    {
      f4v ad = {b3c, b3c, b3c, b3c};
      s8v r3[2];
      r3[0] = *(const s8v*)(pw3);
      #pragma unroll
      for (int kk = 0; kk < 8; kk++){
        if (kk < 7) r3[(kk + 1) & 1] = *(const s8v*)(pw3 + (kk + 1) * 512);
        const s8v a = *(const s8v*)&h1out[m16 * HSTR + kk * 32 + q * 8];
        ad = mfma16(a, r3[kk & 1], ad);
      }
      #pragma unroll
      for (int r = 0; r < 4; r++)
        dstg[(q * 4 + r) * DSTR + w * 16 + m16] = f2bf(gelu(ad[r]));
    }
    __syncthreads();                             // (3) d visible

    // ---- D: out = d @ W4^T + b4 (wave 0) ----
    if (w == 0){
      f4v ao = {0.f, 0.f, 0.f, 0.f};
      #pragma unroll
      for (int kk = 0; kk < 4; kk++){
        const s8v bw = *(const s8v*)(pw4 + kk * 512);
        const s8v a  = *(const s8v*)&dstg[m16 * DSTR + kk * 32 + q * 8];
        ao = mfma16(a, bw, ao);
      }
      if (m16 < 2){
        #pragma unroll
        for (int r = 0; r < 4; r++)
          out[((size_t)(row0 + q * 4 + r) * 256 + t) * 2 + m16] = ao[r] + b4v;
      }
    }
  }
}

extern "C" void kernel_launch(void* const* d_in, const int* in_sizes, int n_in,
                              void* d_out, int out_size, void* d_ws, size_t ws_size,
                              hipStream_t stream)
{
  const float* x    = (const float*)d_in[0];
  const float* W1   = (const float*)d_in[1];
  const float* b1   = (const float*)d_in[2];
  const float* g1   = (const float*)d_in[3];
  const float* be1  = (const float*)d_in[4];
  const float* W2   = (const float*)d_in[5];
  const float* b2   = (const float*)d_in[6];
  const float* g2   = (const float*)d_in[7];
  const float* be2  = (const float*)d_in[8];
  const float* Wih0 = (const float*)d_in[9];
  const float* Whh0 = (const float*)d_in[10];
  const float* bih0 = (const float*)d_in[11];
  const float* bhh0 = (const float*)d_in[12];
  const float* Wih1 = (const float*)d_in[13];
  const float* Whh1 = (const float*)d_in[14];
  const float* bih1 = (const float*)d_in[15];
  const float* bhh1 = (const float*)d_in[16];
  const float* W3   = (const float*)d_in[17];
  const float* b3   = (const float*)d_in[18];
  const float* W4   = (const float*)d_in[19];
  const float* b4   = (const float*)d_in[20];

  short* wsb = (short*)d_ws;

  prep_kernel<<<4232, 256, 0, stream>>>(Wih0, Whh0, Wih1, Whh1, W3, W4, wsb);
  curve_main<<<128, 512, 0, stream>>>(x, W1, b1, g1, be1, W2, b2, g2, be2,
                                      bih0, bhh0, bih1, bhh1, b3, b4, wsb,
                                      (float*)d_out);
}

// Round 7
// 6523.898 us; speedup vs baseline: 2.3637x; 2.3637x over previous
//
#include <hip/hip_runtime.h>
#include <math.h>

// ---------------------------------------------------------------------------
// CurvePredictor R7: batched deep prefetch (16-load SSA batches).
// 64 blocks x 512 threads (8 waves, 2/SIMD, <=256 VGPR), 32 batch rows/block.
// Lesson from R1-R6: every streaming design exposed ~1 miss latency per small
// load group (ring depth <=8 never materialized) -> ~27-38 GB/s per block.
// Fix: load 16 independent B-fragments back-to-back (one waitcnt per 16 KB),
// amortizing the ~700-900cyc L2-miss/IC latency 4x better, with per-ct acc
// scoping so the 64-VGPR batch + 32-VGPR acc + xp/c fit in 256 regs.
// Weights pre-swizzled: each fragment = one fully-coalesced 1 KB wave load.
// Double-buffered h0/h1 in LDS, 3 barriers/step, zero cross-block sync.
// ---------------------------------------------------------------------------

typedef short s8v __attribute__((ext_vector_type(8)));   // 8 x bf16
typedef float f4v __attribute__((ext_vector_type(4)));   // 4 x f32

#define HSTR 264            // LDS h-row stride in shorts (33*16B)
#define DSTR 136

__device__ __forceinline__ f4v mfma16(s8v a, s8v b, f4v c){
  return __builtin_amdgcn_mfma_f32_16x16x32_bf16(a, b, c, 0, 0, 0);
}
__device__ __forceinline__ short f2bf(float f){
  unsigned u = __float_as_uint(f);
  u = u + 0x7FFFu + ((u >> 16) & 1u);
  return (short)(u >> 16);
}
__device__ __forceinline__ float wred(float v){
  #pragma unroll
  for (int o = 32; o; o >>= 1) v += __shfl_xor(v, o);
  return v;
}
__device__ __forceinline__ float sigm(float x){ return 1.0f / (1.0f + __expf(-x)); }
__device__ __forceinline__ float tnh(float x){
  x = fminf(15.0f, fmaxf(-15.0f, x));
  float e = __expf(2.0f * x);
  return (e - 1.0f) / (e + 1.0f);
}
__device__ __forceinline__ float gelu(float v){
  return 0.5f * v * (1.0f + erff(v * 0.70710678118654752440f));
}

// ws layout (shorts), swizzled for coalesced B-frag loads (same as R5/R6):
// main matrices (1024x256): elem = s*16384 + g*4096 + kk*512 + lane*8 + j
//   lane = q*16+m16, hid = s*16+m16, k = kk*32+q*8+j, gate-row = g*256+hid
//   [0,262144) Wih0  [262144,524288) Whh0  [524288,786432) Wih1  [786432,1048576) Whh1
// W3 [128][256]: 1048576 + s2*4096 + kk*512 + lane*8  (row = s2*16+m16)
// W4 padded [16][128]: 1081344 + kk*512 + lane*8      (row = m16, kk<4)
__global__ void prep_kernel(
    const float* __restrict__ Wih0, const float* __restrict__ Whh0,
    const float* __restrict__ Wih1, const float* __restrict__ Whh1,
    const float* __restrict__ W3,   const float* __restrict__ W4,
    short* __restrict__ wsb)
{
  const int i = blockIdx.x * 256 + threadIdx.x;
  if (i >= 1083392) return;
  float v;
  if (i < 1048576){
    const int seg = i >> 18;
    const int r   = i & 262143;
    const int s   = r >> 14;
    const int g   = (r >> 12) & 3;
    const int kk  = (r >> 9) & 7;
    const int q   = (r >> 7) & 3;
    const int m16 = (r >> 3) & 15;
    const int j   = r & 7;
    const int hid = s * 16 + m16;
    const int k   = kk * 32 + q * 8 + j;
    const float* mt = (seg == 0) ? Wih0 : (seg == 1) ? Whh0 : (seg == 2) ? Wih1 : Whh1;
    v = mt[(g * 256 + hid) * 256 + k];
  } else if (i < 1081344){
    const int r   = i - 1048576;
    const int s2  = r >> 12;
    const int kk  = (r >> 9) & 7;
    const int q   = (r >> 7) & 3;
    const int m16 = (r >> 3) & 15;
    const int j   = r & 7;
    v = W3[(s2 * 16 + m16) * 256 + kk * 32 + q * 8 + j];
  } else {
    const int r   = i - 1081344;
    const int kk  = (r >> 9) & 3;
    const int q   = (r >> 7) & 3;
    const int m16 = (r >> 3) & 15;
    const int j   = r & 7;
    const int k   = kk * 32 + q * 8 + j;
    v = (m16 < 2) ? W4[m16 * 128 + k] : 0.0f;
  }
  wsb[i] = f2bf(v);
}

// One 16-col slice of one matrix, 32 batch rows, K=256, acc[rt][gate].
// Two explicit 16-load batches: all 16 issued back-to-back (SSA forces
// parallel issue; one waitcnt per 16KB), consumed by 32 MFMAs each.
__device__ __forceinline__ void gemm_ct(
    const short* __restrict__ hA, const short* __restrict__ pw,
    int m16, int q, f4v (&acc)[2][4])
{
  {
    s8v B0[16];
    #pragma unroll
    for (int f = 0; f < 16; f++)
      B0[f] = *(const s8v*)(pw + (f & 3) * 4096 + (f >> 2) * 512);
    #pragma unroll
    for (int kk = 0; kk < 4; kk++){
      const s8v a0 = *(const s8v*)&hA[ m16       * HSTR + kk * 32 + q * 8];
      const s8v a1 = *(const s8v*)&hA[(16 + m16) * HSTR + kk * 32 + q * 8];
      #pragma unroll
      for (int g = 0; g < 4; g++){
        acc[0][g] = mfma16(a0, B0[kk * 4 + g], acc[0][g]);
        acc[1][g] = mfma16(a1, B0[kk * 4 + g], acc[1][g]);
      }
    }
  }
  {
    s8v B1[16];
    #pragma unroll
    for (int f = 0; f < 16; f++)
      B1[f] = *(const s8v*)(pw + (f & 3) * 4096 + (4 + (f >> 2)) * 512);
    #pragma unroll
    for (int kk = 0; kk < 4; kk++){
      const s8v a0 = *(const s8v*)&hA[ m16       * HSTR + (kk + 4) * 32 + q * 8];
      const s8v a1 = *(const s8v*)&hA[(16 + m16) * HSTR + (kk + 4) * 32 + q * 8];
      #pragma unroll
      for (int g = 0; g < 4; g++){
        acc[0][g] = mfma16(a0, B1[kk * 4 + g], acc[0][g]);
        acc[1][g] = mfma16(a1, B1[kk * 4 + g], acc[1][g]);
      }
    }
  }
}

__global__ __launch_bounds__(512) void curve_main(
    const float* __restrict__ x,
    const float* __restrict__ W1, const float* __restrict__ b1,
    const float* __restrict__ g1, const float* __restrict__ be1,
    const float* __restrict__ W2, const float* __restrict__ b2,
    const float* __restrict__ g2, const float* __restrict__ be2,
    const float* __restrict__ bih0, const float* __restrict__ bhh0,
    const float* __restrict__ bih1, const float* __restrict__ bhh1,
    const float* __restrict__ b3, const float* __restrict__ b4,
    const short* __restrict__ wsb,
    float* __restrict__ out)
{
  const int tid  = threadIdx.x;
  const int w    = tid >> 6;        // wave 0..7 <-> 32-col hidden slice
  const int lane = tid & 63;
  const int q    = lane >> 4;
  const int m16  = lane & 15;
  const int row0 = blockIdx.x * 32;

  __shared__ __align__(16) short h0b[2][32 * HSTR];
  __shared__ __align__(16) short h1b[2][32 * HSTR];
  __shared__ __align__(16) short dstg[32 * DSTR];

  // --------- encoder: wave w computes batch rows row0 + u*8 + w ------------
  #pragma unroll 1
  for (int u = 0; u < 4; u++){
    const int rr = u * 8 + w;
    const int r  = row0 + rr;
    float xv[5];
    #pragma unroll
    for (int k = 0; k < 5; k++) xv[k] = x[r * 5 + k];
    float a0 = b1[lane], a1 = b1[lane + 64];
    #pragma unroll
    for (int k = 0; k < 5; k++){
      a0 += xv[k] * W1[lane * 5 + k];
      a1 += xv[k] * W1[(lane + 64) * 5 + k];
    }
    a0 = gelu(a0); a1 = gelu(a1);
    float mean = wred(a0 + a1) * (1.0f / 128.0f);
    float d0 = a0 - mean, d1 = a1 - mean;
    float inv = rsqrtf(wred(d0 * d0 + d1 * d1) * (1.0f / 128.0f) + 1e-5f);
    float y0 = d0 * inv * g1[lane]      + be1[lane];
    float y1 = d1 * inv * g1[lane + 64] + be1[lane + 64];

    float acc2[4];
    #pragma unroll
    for (int uu = 0; uu < 4; uu++) acc2[uu] = b2[lane + 64 * uu];
    for (int k = 0; k < 64; k++){
      float v0 = __shfl(y0, k);
      float v1 = __shfl(y1, k);
      #pragma unroll
      for (int uu = 0; uu < 4; uu++){
        const float* wr = W2 + (lane + 64 * uu) * 128;
        acc2[uu] += v0 * wr[k] + v1 * wr[k + 64];
      }
    }
    #pragma unroll
    for (int uu = 0; uu < 4; uu++) acc2[uu] = gelu(acc2[uu]);
    float s = acc2[0] + acc2[1] + acc2[2] + acc2[3];
    mean = wred(s) * (1.0f / 256.0f);
    float vv = 0.0f;
    #pragma unroll
    for (int uu = 0; uu < 4; uu++){ float d = acc2[uu] - mean; vv += d * d; }
    inv = rsqrtf(wred(vv) * (1.0f / 256.0f) + 1e-5f);
    #pragma unroll
    for (int uu = 0; uu < 4; uu++){
      int c = lane + 64 * uu;
      float e = (acc2[uu] - mean) * inv * g2[c] + be2[c];
      h0b[0][rr * HSTR + c] = f2bf(e);       // enc staged in h0 slot 0
    }
  }
  __syncthreads();

  // swizzled slice bases: slice s = 2w+ct, per-lane offset lane*16B
  const short* pwi0 = wsb            + (2 * w) * 16384 + (lane << 3);
  const short* pwh0 = wsb +  262144  + (2 * w) * 16384 + (lane << 3);
  const short* pwi1 = wsb +  524288  + (2 * w) * 16384 + (lane << 3);
  const short* pwh1 = wsb +  786432  + (2 * w) * 16384 + (lane << 3);
  const short* pw3  = wsb + 1048576  + w * 4096 + (lane << 3);
  const short* pw4  = wsb + 1081344  + (lane << 3);

  // ---- xp0 = enc @ Wih0_slice^T + (bih0+bhh0), kept in registers ----
  f4v xp[2][2][4];                      // [ct][rt][gate]
  #pragma unroll 1
  for (int ct = 0; ct < 2; ct++){
    f4v acc[2][4];
    #pragma unroll
    for (int g = 0; g < 4; g++){
      const int n = g * 256 + w * 32 + ct * 16 + m16;
      const float bi = bih0[n] + bhh0[n];
      f4v t = {bi, bi, bi, bi};
      acc[0][g] = t; acc[1][g] = t;
    }
    gemm_ct(&h0b[0][0], pwi0 + ct * 16384, m16, q, acc);
    #pragma unroll
    for (int rt = 0; rt < 2; rt++)
      #pragma unroll
      for (int g = 0; g < 4; g++) xp[ct][rt][g] = acc[rt][g];
  }
  __syncthreads();
  for (int i = tid; i < 32 * HSTR; i += 512){ h0b[0][i] = 0; h1b[0][i] = 0; }

  float bs1[2][4];
  #pragma unroll
  for (int ct = 0; ct < 2; ct++)
    #pragma unroll
    for (int g = 0; g < 4; g++){
      const int n = g * 256 + w * 32 + ct * 16 + m16;
      bs1[ct][g] = bih1[n] + bhh1[n];
    }
  const float b3c = b3[w * 16 + m16];
  const float b4v = (m16 < 2) ? b4[m16] : 0.0f;
  float c0[2][2][4], c1[2][2][4];       // [ct][rt][r]
  #pragma unroll
  for (int ct = 0; ct < 2; ct++)
    #pragma unroll
    for (int rt = 0; rt < 2; rt++)
      #pragma unroll
      for (int r = 0; r < 4; r++){ c0[ct][rt][r] = 0.f; c1[ct][rt][r] = 0.f; }
  __syncthreads();

  // --------------------------- recurrence over T ---------------------------
  #pragma unroll 1
  for (int t = 0; t < 256; t++){
    const short* h0in  = h0b[t & 1];
    short*       h0out = h0b[(t + 1) & 1];
    const short* h1in  = h1b[t & 1];
    short*       h1out = h1b[(t + 1) & 1];

    // ---- A: gates0 = xp0 + h0_old @ Whh0^T -> c0, h0_new ----
    #pragma unroll 1
    for (int ct = 0; ct < 2; ct++){
      f4v acc[2][4];
      #pragma unroll
      for (int rt = 0; rt < 2; rt++)
        #pragma unroll
        for (int g = 0; g < 4; g++) acc[rt][g] = xp[ct][rt][g];
      gemm_ct(h0in, pwh0 + ct * 16384, m16, q, acc);
      #pragma unroll
      for (int rt = 0; rt < 2; rt++)
        #pragma unroll
        for (int r = 0; r < 4; r++){
          float ii = sigm(acc[rt][0][r]);
          float ff = sigm(acc[rt][1][r]);
          float gg = tnh (acc[rt][2][r]);
          float oo = sigm(acc[rt][3][r]);
          c0[ct][rt][r] = ff * c0[ct][rt][r] + ii * gg;
          h0out[(rt * 16 + q * 4 + r) * HSTR + w * 32 + ct * 16 + m16] =
              f2bf(oo * tnh(c0[ct][rt][r]));
        }
    }
    __syncthreads();                             // (1) h0_new visible

    // ---- B: gates1 = bias1 + h0_new@Wih1^T + h1_old@Whh1^T -> c1, h1_new --
    #pragma unroll 1
    for (int ct = 0; ct < 2; ct++){
      f4v acc[2][4];
      #pragma unroll
      for (int rt = 0; rt < 2; rt++)
        #pragma unroll
        for (int g = 0; g < 4; g++){
          f4v tv = {bs1[ct][g], bs1[ct][g], bs1[ct][g], bs1[ct][g]};
          acc[rt][g] = tv;
        }
      gemm_ct(h0out, pwi1 + ct * 16384, m16, q, acc);
      gemm_ct(h1in,  pwh1 + ct * 16384, m16, q, acc);
      #pragma unroll
      for (int rt = 0; rt < 2; rt++)
        #pragma unroll
        for (int r = 0; r < 4; r++){
          float ii = sigm(acc[rt][0][r]);
          float ff = sigm(acc[rt][1][r]);
          float gg = tnh (acc[rt][2][r]);
          float oo = sigm(acc[rt][3][r]);
          c1[ct][rt][r] = ff * c1[ct][rt][r] + ii * gg;
          h1out[(rt * 16 + q * 4 + r) * HSTR + w * 32 + ct * 16 + m16] =
              f2bf(oo * tnh(c1[ct][rt][r]));
        }
    }
    __syncthreads();                             // (2) h1_new visible

    // ---- C: d = gelu(h1_new @ W3^T + b3), wave w -> d cols w*16+m16 ----
    {
      s8v B3[8];
      #pragma unroll
      for (int f = 0; f < 8; f++) B3[f] = *(const s8v*)(pw3 + f * 512);
      f4v ad0 = {b3c, b3c, b3c, b3c};
      f4v ad1 = ad0;
      #pragma unroll
      for (int kk = 0; kk < 8; kk++){
        const s8v a0 = *(const s8v*)&h1out[ m16       * HSTR + kk * 32 + q * 8];
        const s8v a1 = *(const s8v*)&h1out[(16 + m16) * HSTR + kk * 32 + q * 8];
        ad0 = mfma16(a0, B3[kk], ad0);
        ad1 = mfma16(a1, B3[kk], ad1);
      }
      #pragma unroll
      for (int r = 0; r < 4; r++){
        dstg[( q * 4 + r)      * DSTR + w * 16 + m16] = f2bf(gelu(ad0[r]));
        dstg[(16 + q * 4 + r)  * DSTR + w * 16 + m16] = f2bf(gelu(ad1[r]));
      }
    }
    __syncthreads();                             // (3) d visible

    // ---- D: out = d @ W4^T + b4 (waves 0,1; rt = w) ----
    if (w < 2){
      const int rt = w;
      f4v ao = {0.f, 0.f, 0.f, 0.f};
      #pragma unroll
      for (int kk = 0; kk < 4; kk++){
        const s8v bw = *(const s8v*)(pw4 + kk * 512);
        const s8v a  = *(const s8v*)&dstg[(rt * 16 + m16) * DSTR + kk * 32 + q * 8];
        ao = mfma16(a, bw, ao);
      }
      if (m16 < 2){
        #pragma unroll
        for (int r = 0; r < 4; r++)
          out[((size_t)(row0 + rt * 16 + q * 4 + r) * 256 + t) * 2 + m16] = ao[r] + b4v;
      }
    }
  }
}

extern "C" void kernel_launch(void* const* d_in, const int* in_sizes, int n_in,
                              void* d_out, int out_size, void* d_ws, size_t ws_size,
                              hipStream_t stream)
{
  const float* x    = (const float*)d_in[0];
  const float* W1   = (const float*)d_in[1];
  const float* b1   = (const float*)d_in[2];
  const float* g1   = (const float*)d_in[3];
  const float* be1  = (const float*)d_in[4];
  const float* W2   = (const float*)d_in[5];
  const float* b2   = (const float*)d_in[6];
  const float* g2   = (const float*)d_in[7];
  const float* be2  = (const float*)d_in[8];
  const float* Wih0 = (const float*)d_in[9];
  const float* Whh0 = (const float*)d_in[10];
  const float* bih0 = (const float*)d_in[11];
  const float* bhh0 = (const float*)d_in[12];
  const float* Wih1 = (const float*)d_in[13];
  const float* Whh1 = (const float*)d_in[14];
  const float* bih1 = (const float*)d_in[15];
  const float* bhh1 = (const float*)d_in[16];
  const float* W3   = (const float*)d_in[17];
  const float* b3   = (const float*)d_in[18];
  const float* W4   = (const float*)d_in[19];
  const float* b4   = (const float*)d_in[20];

  short* wsb = (short*)d_ws;

  prep_kernel<<<4232, 256, 0, stream>>>(Wih0, Whh0, Wih1, Whh1, W3, W4, wsb);
  curve_main<<<64, 512, 0, stream>>>(x, W1, b1, g1, be1, W2, b2, g2, be2,
                                     bih0, bhh0, bih1, bhh1, b3, b4, wsb,
                                     (float*)d_out);
}